// Round 2
// baseline (428.748 us; speedup 1.0000x reference)
//
#include <hip/hip_runtime.h>

typedef unsigned short u16;
typedef __attribute__((ext_vector_type(8))) short short8;   // 8 x bf16 (4 VGPRs)
typedef __attribute__((ext_vector_type(4))) short short4v;
typedef __attribute__((ext_vector_type(4))) float f32x4;

#define B_  4
#define T_  2048
#define D_  1024
#define H_  16
#define HS_ 64
#define M_    (B_ * T_)        /* 8192 */
#define NQKV_ (H_ * 3 * HS_)   /* 3072 */
#define NTILE_ (T_ / 64)       /* 32 */

__device__ __forceinline__ u16 f2bf(float f) {
  union { float f; unsigned u; } v; v.f = f;
  unsigned u = v.u;
  return (u16)((u + 0x7FFFu + ((u >> 16) & 1u)) >> 16);  // RNE
}
__device__ __forceinline__ float bf2f(u16 h) {
  union { unsigned u; float f; } v; v.u = ((unsigned)h) << 16; return v.f;
}

// ---------------- convert x (fp32) -> bf16 ----------------
__global__ void k_cvt_x(const float* __restrict__ x, u16* __restrict__ o, int n4) {
  int i = blockIdx.x * 256 + threadIdx.x;
  if (i < n4) {
    float4 v = ((const float4*)x)[i];
    short4v d;
    d[0] = (short)f2bf(v.x); d[1] = (short)f2bf(v.y);
    d[2] = (short)f2bf(v.z); d[3] = (short)f2bf(v.w);
    ((short4v*)o)[i] = d;
  }
}

// ------- transpose+convert: in fp32 [R][C] (+h*sIn) -> out bf16 [C][R] (+h*sOut) -------
__global__ void k_transpose_cvt(const float* __restrict__ in, u16* __restrict__ out,
                                int R, int C, long sIn, long sOut) {
  __shared__ float tile[32][33];
  int h = blockIdx.z;
  const float* src = in + (long)h * sIn;
  u16* dst = out + (long)h * sOut;
  int r0 = blockIdx.y * 32, c0 = blockIdx.x * 32;
  int tx = threadIdx.x, ty = threadIdx.y;  // 32 x 8
  #pragma unroll
  for (int i = 0; i < 32; i += 8) {
    int r = r0 + ty + i, c = c0 + tx;
    tile[ty + i][tx] = (r < R && c < C) ? src[(long)r * C + c] : 0.f;
  }
  __syncthreads();
  #pragma unroll
  for (int i = 0; i < 32; i += 8) {
    int c = c0 + ty + i, r = r0 + tx;
    if (c < C && r < R) dst[(long)c * R + r] = f2bf(tile[tx][ty + i]);
  }
}

// ---------------- GEMM: C[M][N] = A[M][K] @ Bt[N][K]^T (bf16 in, fp32 acc) ----------------
// MODE 0: scatter epilogue -> Q(*1/32), K, V  [B,H,T,64] bf16.  MODE 1: fp32 row-major out.
template<int MODE>
__global__ __launch_bounds__(256) void k_gemm(
    const u16* __restrict__ A, const u16* __restrict__ Bt,
    u16* __restrict__ Oq, u16* __restrict__ Ok, u16* __restrict__ Ov,
    float* __restrict__ Of, int K) {
  constexpr int LDK = 40;  // 32 + 8 pad, keeps 16B alignment, breaks pow2 bank stride
  __shared__ __align__(16) u16 As[128 * LDK];
  __shared__ __align__(16) u16 Bs[128 * LDK];
  int mt = blockIdx.x, nt = blockIdx.y;
  int tid = threadIdx.x;
  int wid = tid >> 6, lane = tid & 63;
  int lr = lane & 15, lg = lane >> 4;
  int mw = (wid >> 1) * 64, nw = (wid & 1) * 64;
  int arow = tid >> 1, acol = (tid & 1) * 16;
  const long aBase = (long)(mt * 128 + arow) * K + acol;
  const long bBase = (long)(nt * 128 + arow) * K + acol;
  f32x4 acc[4][4] = {};
  for (int k0 = 0; k0 < K; k0 += 32) {
    short8 av0 = *(const short8*)(A + aBase + k0);
    short8 av1 = *(const short8*)(A + aBase + k0 + 8);
    short8 bv0 = *(const short8*)(Bt + bBase + k0);
    short8 bv1 = *(const short8*)(Bt + bBase + k0 + 8);
    __syncthreads();
    *(short8*)(As + arow * LDK + acol)     = av0;
    *(short8*)(As + arow * LDK + acol + 8) = av1;
    *(short8*)(Bs + arow * LDK + acol)     = bv0;
    *(short8*)(Bs + arow * LDK + acol + 8) = bv1;
    __syncthreads();
    short8 af[4], bf[4];
    #pragma unroll
    for (int i = 0; i < 4; i++)
      af[i] = *(const short8*)(As + (mw + i * 16 + lr) * LDK + lg * 8);
    #pragma unroll
    for (int i = 0; i < 4; i++)
      bf[i] = *(const short8*)(Bs + (nw + i * 16 + lr) * LDK + lg * 8);
    #pragma unroll
    for (int i = 0; i < 4; i++)
      #pragma unroll
      for (int j = 0; j < 4; j++)
        acc[i][j] = __builtin_amdgcn_mfma_f32_16x16x32_bf16(af[i], bf[j], acc[i][j], 0, 0, 0);
  }
  #pragma unroll
  for (int i = 0; i < 4; i++) {
    #pragma unroll
    for (int j = 0; j < 4; j++) {
      int mbase = mt * 128 + mw + i * 16 + lg * 4;      // C/D: row=(lane>>4)*4+r
      int n     = nt * 128 + nw + j * 16 + lr;          //      col=lane&15
      #pragma unroll
      for (int r = 0; r < 4; r++) {
        float val = acc[i][j][r];
        int m = mbase + r;
        if (MODE == 0) {
          int b = m >> 11, t = m & (T_ - 1);
          int h = n / 192, f = n % 192;
          long o = (((long)(b * H_ + h)) * T_ + t) * HS_;
          if (f < 64)       Oq[o + f]       = f2bf(val * 0.03125f);  // fold C^-0.5
          else if (f < 128) Ok[o + f - 64]  = f2bf(val);
          else              Ov[o + f - 128] = f2bf(val);
        } else {
          Of[(long)m * D_ + n] = val;
        }
      }
    }
  }
}

// ---------------- transpose V [bh][T][64] -> Vt [bh][64][T] ----------------
__global__ void k_transpose_v(const u16* __restrict__ V, u16* __restrict__ Vt) {
  __shared__ u16 tile[64][65];
  int bh = blockIdx.z;
  int t0 = blockIdx.x * 64;
  int tx = threadIdx.x & 63, ty = threadIdx.x >> 6;
  const u16* src = V + (long)bh * T_ * HS_;
  u16* dst = Vt + (long)bh * T_ * HS_;
  #pragma unroll
  for (int i = 0; i < 64; i += 4)
    tile[ty + i][tx] = src[(long)(t0 + ty + i) * HS_ + tx];
  __syncthreads();
  #pragma unroll
  for (int i = 0; i < 64; i += 4)
    dst[(long)(ty + i) * T_ + t0 + tx] = tile[tx][ty + i];
}

// -------- V suffix sums at tile granularity: Suf[bh][j][d] = sum_{s >= j*64} V[bh][s][d] --------
// grid: B*H blocks, 64 threads (one wave); thread d owns dim d. Coalesced 128B reads per s.
__global__ void k_vsuffix(const u16* __restrict__ V, float* __restrict__ Suf) {
  int bh = blockIdx.x;
  int d = threadIdx.x;
  const u16* Vb = V + (long)bh * T_ * HS_;
  float* Sb = Suf + (long)bh * (NTILE_ + 1) * HS_;
  float acc = 0.f;
  Sb[NTILE_ * HS_ + d] = 0.f;
  for (int j = NTILE_ - 1; j >= 0; j--) {
    #pragma unroll 8
    for (int i = 63; i >= 0; i--)
      acc += bf2f(Vb[(long)(j * 64 + i) * HS_ + d]);
    Sb[j * HS_ + d] = acc;
  }
}

// ---------------- fused attention: causal tiles + closed-form masked-suffix correction ----------------
// masked_fill(1e-9) semantics: masked entries contribute exp(1e-9 - m) each;
// for s >= (qt+1)*64 that's  nmask*exp(1e-9-m) to l  and  exp(1e-9-m)*Suf to o.
__global__ __launch_bounds__(256) void k_attn(
    const u16* __restrict__ Q, const u16* __restrict__ Kc,
    const u16* __restrict__ Vt, const float* __restrict__ Suf,
    u16* __restrict__ Mha) {
  __shared__ __align__(16) u16 Ks[64 * 72];
  __shared__ __align__(16) u16 Vs[64 * 72];
  __shared__ __align__(16) u16 Ps[4][16 * 72];
  int qt = (int)gridDim.x - 1 - (int)blockIdx.x;  // heavy tiles dispatch first
  int bh = blockIdx.y;
  int b = bh >> 4, h = bh & 15;
  int tid = threadIdx.x, wid = tid >> 6, lane = tid & 63;
  int lr = lane & 15, lg = lane >> 4;
  const u16* Qb = Q  + (long)bh * T_ * HS_;
  const u16* Kb = Kc + (long)bh * T_ * HS_;
  const u16* Vb = Vt + (long)bh * T_ * HS_;   // [64][T]
  int qrow = qt * 64 + wid * 16 + lr;         // A-operand: m = lane&15
  short8 qf0 = *(const short8*)(Qb + (long)qrow * HS_ + lg * 8);
  short8 qf1 = *(const short8*)(Qb + (long)qrow * HS_ + 32 + lg * 8);
  f32x4 accO[4] = {};                         // rows lg*4+r, cols fd*16+lr
  float mrun[4], lrun[4];
  #pragma unroll
  for (int r = 0; r < 4; r++) { mrun[r] = 1e-9f; lrun[r] = 0.f; }  // init covers masked max
  int srow = tid >> 2, scol = (tid & 3) * 16;
  const int jend = qt * 64;
  for (int j0 = 0; j0 <= jend; j0 += 64) {
    const bool diag = (j0 == jend);
    __syncthreads();
    *(short8*)(Ks + srow * 72 + scol)     = *(const short8*)(Kb + (long)(j0 + srow) * HS_ + scol);
    *(short8*)(Ks + srow * 72 + scol + 8) = *(const short8*)(Kb + (long)(j0 + srow) * HS_ + scol + 8);
    *(short8*)(Vs + srow * 72 + scol)     = *(const short8*)(Vb + (long)srow * T_ + j0 + scol);
    *(short8*)(Vs + srow * 72 + scol + 8) = *(const short8*)(Vb + (long)srow * T_ + j0 + scol + 8);
    __syncthreads();
    // S = Q K^T  (scale already folded into Q)
    f32x4 s4[4];
    #pragma unroll
    for (int fn = 0; fn < 4; fn++) {
      short8 kb0 = *(const short8*)(Ks + (fn * 16 + lr) * 72 + lg * 8);
      short8 kb1 = *(const short8*)(Ks + (fn * 16 + lr) * 72 + 32 + lg * 8);
      f32x4 z = {};
      z = __builtin_amdgcn_mfma_f32_16x16x32_bf16(qf0, kb0, z, 0, 0, 0);
      z = __builtin_amdgcn_mfma_f32_16x16x32_bf16(qf1, kb1, z, 0, 0, 0);
      s4[fn] = z;
    }
    // online softmax (rows live on 16 lanes sharing lg; reduce over lr via shfl_xor)
    float scl[4];
    float pv[4][4];
    #pragma unroll
    for (int r = 0; r < 4; r++) {
      float vals[4];
      if (diag) {
        int trow = qt * 64 + wid * 16 + lg * 4 + r;
        #pragma unroll
        for (int fn = 0; fn < 4; fn++) {
          int s = j0 + fn * 16 + lr;
          vals[fn] = (s <= trow) ? s4[fn][r] : 1e-9f;   // faithful masked_fill(1e-9)
        }
      } else {
        #pragma unroll
        for (int fn = 0; fn < 4; fn++) vals[fn] = s4[fn][r];
      }
      float tmax = fmaxf(fmaxf(vals[0], vals[1]), fmaxf(vals[2], vals[3]));
      #pragma unroll
      for (int sh = 1; sh < 16; sh <<= 1)
        tmax = fmaxf(tmax, __shfl_xor(tmax, sh, 64));
      float mn = fmaxf(mrun[r], tmax);
      scl[r] = __expf(mrun[r] - mn);
      mrun[r] = mn;
      float psum = 0.f;
      #pragma unroll
      for (int fn = 0; fn < 4; fn++) {
        float pe = __expf(vals[fn] - mn);
        pv[fn][r] = pe;
        psum += pe;
      }
      #pragma unroll
      for (int sh = 1; sh < 16; sh <<= 1)
        psum += __shfl_xor(psum, sh, 64);
      lrun[r] = lrun[r] * scl[r] + psum;
    }
    #pragma unroll
    for (int fd = 0; fd < 4; fd++)
      #pragma unroll
      for (int r = 0; r < 4; r++)
        accO[fd][r] *= scl[r];
    // P: D-layout -> A-layout via per-wave LDS bounce
    #pragma unroll
    for (int fn = 0; fn < 4; fn++)
      #pragma unroll
      for (int r = 0; r < 4; r++)
        Ps[wid][(lg * 4 + r) * 72 + fn * 16 + lr] = f2bf(pv[fn][r]);
    short8 pa0 = *(const short8*)(&Ps[wid][lr * 72 + lg * 8]);
    short8 pa1 = *(const short8*)(&Ps[wid][lr * 72 + 32 + lg * 8]);
    #pragma unroll
    for (int fd = 0; fd < 4; fd++) {
      short8 vb0 = *(const short8*)(Vs + (fd * 16 + lr) * 72 + lg * 8);
      short8 vb1 = *(const short8*)(Vs + (fd * 16 + lr) * 72 + 32 + lg * 8);
      accO[fd] = __builtin_amdgcn_mfma_f32_16x16x32_bf16(pa0, vb0, accO[fd], 0, 0, 0);
      accO[fd] = __builtin_amdgcn_mfma_f32_16x16x32_bf16(pa1, vb1, accO[fd], 0, 0, 0);
    }
  }
  // -------- closed-form correction for fully-masked suffix tiles --------
  {
    int nmask = T_ - (qt + 1) * 64;
    const float* sufp = Suf + ((long)bh * (NTILE_ + 1) + (qt + 1)) * HS_;
    float sufv[4];
    #pragma unroll
    for (int fd = 0; fd < 4; fd++) sufv[fd] = sufp[fd * 16 + lr];
    #pragma unroll
    for (int r = 0; r < 4; r++) {
      float pm = __expf(1e-9f - mrun[r]);
      lrun[r] += (float)nmask * pm;
      #pragma unroll
      for (int fd = 0; fd < 4; fd++)
        accO[fd][r] += pm * sufv[fd];
    }
  }
  #pragma unroll
  for (int fd = 0; fd < 4; fd++) {
    #pragma unroll
    for (int r = 0; r < 4; r++) {
      int trow = qt * 64 + wid * 16 + lg * 4 + r;
      int dcol = fd * 16 + lr;
      float o = accO[fd][r] / lrun[r];
      Mha[((long)(b * T_ + trow)) * D_ + h * HS_ + dcol] = f2bf(o);
    }
  }
}

extern "C" void kernel_launch(void* const* d_in, const int* in_sizes, int n_in,
                              void* d_out, int out_size, void* d_ws, size_t ws_size,
                              hipStream_t stream) {
  const float* x    = (const float*)d_in[0];
  const float* wqkv = (const float*)d_in[1];   // [16][1024][192]
  const float* wout = (const float*)d_in[2];   // [1024][1024]
  float* out = (float*)d_out;

  char* p = (char*)d_ws;
  u16* Xb    = (u16*)p; p += (size_t)M_ * D_ * 2;        // x as bf16 [8192][1024]
  u16* WqkvT = (u16*)p; p += (size_t)NQKV_ * D_ * 2;     // [3072][1024]  (n-major, k-contig)
  u16* WoutT = (u16*)p; p += (size_t)D_ * D_ * 2;        // [1024][1024]  W_out^T
  u16* Qw  = (u16*)p; p += (size_t)B_ * H_ * T_ * HS_ * 2;  // [B,H,T,64], pre-scaled
  u16* Kw  = (u16*)p; p += (size_t)B_ * H_ * T_ * HS_ * 2;
  u16* Vw  = (u16*)p; p += (size_t)B_ * H_ * T_ * HS_ * 2;
  u16* Vtw = (u16*)p; p += (size_t)B_ * H_ * T_ * HS_ * 2;  // [B,H,64,T]
  u16* Mha = (u16*)p; p += (size_t)M_ * D_ * 2;             // [8192][1024]
  float* Suf = (float*)p; p += (size_t)B_ * H_ * (NTILE_ + 1) * HS_ * 4;  // [bh][33][64] fp32

  k_cvt_x<<<dim3(M_ * D_ / 4 / 256), dim3(256), 0, stream>>>(x, Xb, M_ * D_ / 4);
  k_transpose_cvt<<<dim3(192 / 32, D_ / 32, H_), dim3(32, 8), 0, stream>>>(
      wqkv, WqkvT, D_, 192, (long)D_ * 192, (long)192 * D_);
  k_transpose_cvt<<<dim3(D_ / 32, D_ / 32, 1), dim3(32, 8), 0, stream>>>(
      wout, WoutT, D_, D_, 0, 0);
  k_gemm<0><<<dim3(M_ / 128, NQKV_ / 128), dim3(256), 0, stream>>>(
      Xb, WqkvT, Qw, Kw, Vw, nullptr, D_);
  k_transpose_v<<<dim3(T_ / 64, 1, B_ * H_), dim3(256), 0, stream>>>(Vw, Vtw);
  k_vsuffix<<<dim3(B_ * H_), dim3(64), 0, stream>>>(Vw, Suf);
  k_attn<<<dim3(NTILE_, B_ * H_), dim3(256), 0, stream>>>(Qw, Kw, Vtw, Suf, Mha);
  k_gemm<1><<<dim3(M_ / 128, D_ / 128), dim3(256), 0, stream>>>(
      Mha, WoutT, nullptr, nullptr, nullptr, out, D_);
}

// Round 3
// 273.456 us; speedup vs baseline: 1.5679x; 1.5679x over previous
//
#include <hip/hip_runtime.h>

typedef unsigned short u16;
typedef __attribute__((ext_vector_type(8))) short short8;   // 8 x bf16 (4 VGPRs)
typedef __attribute__((ext_vector_type(4))) short short4v;
typedef __attribute__((ext_vector_type(4))) float f32x4;

#define B_  4
#define T_  2048
#define D_  1024
#define H_  16
#define HS_ 64
#define M_    (B_ * T_)        /* 8192 */
#define NQKV_ (H_ * 3 * HS_)   /* 3072 */
#define NTILE_ (T_ / 64)       /* 32 */

__device__ __forceinline__ u16 f2bf(float f) {
  union { float f; unsigned u; } v; v.f = f;
  unsigned u = v.u;
  return (u16)((u + 0x7FFFu + ((u >> 16) & 1u)) >> 16);  // RNE
}
__device__ __forceinline__ float bf2f(u16 h) {
  union { unsigned u; float f; } v; v.u = ((unsigned)h) << 16; return v.f;
}

// ---------------- convert x (fp32) -> bf16 ----------------
__global__ void k_cvt_x(const float* __restrict__ x, u16* __restrict__ o, int n4) {
  int i = blockIdx.x * 256 + threadIdx.x;
  if (i < n4) {
    float4 v = ((const float4*)x)[i];
    short4v d;
    d[0] = (short)f2bf(v.x); d[1] = (short)f2bf(v.y);
    d[2] = (short)f2bf(v.z); d[3] = (short)f2bf(v.w);
    ((short4v*)o)[i] = d;
  }
}

// ------- transpose+convert: in fp32 [R][C] (+h*sIn) -> out bf16 [C][R] (+h*sOut) -------
__global__ void k_transpose_cvt(const float* __restrict__ in, u16* __restrict__ out,
                                int R, int C, long sIn, long sOut) {
  __shared__ float tile[32][33];
  int h = blockIdx.z;
  const float* src = in + (long)h * sIn;
  u16* dst = out + (long)h * sOut;
  int r0 = blockIdx.y * 32, c0 = blockIdx.x * 32;
  int tx = threadIdx.x, ty = threadIdx.y;  // 32 x 8
  #pragma unroll
  for (int i = 0; i < 32; i += 8) {
    int r = r0 + ty + i, c = c0 + tx;
    tile[ty + i][tx] = (r < R && c < C) ? src[(long)r * C + c] : 0.f;
  }
  __syncthreads();
  #pragma unroll
  for (int i = 0; i < 32; i += 8) {
    int c = c0 + ty + i, r = r0 + tx;
    if (c < C && r < R) dst[(long)c * R + r] = f2bf(tile[tx][ty + i]);
  }
}

// ---------------- GEMM: C[M][N] = A[M][K] @ Bt[N][K]^T (bf16 in, fp32 acc) ----------------
// MODE 0: scatter epilogue -> Q(*1/32), K, V  [B,H,T,64] bf16.  MODE 1: fp32 row-major out.
template<int MODE>
__global__ __launch_bounds__(256) void k_gemm(
    const u16* __restrict__ A, const u16* __restrict__ Bt,
    u16* __restrict__ Oq, u16* __restrict__ Ok, u16* __restrict__ Ov,
    float* __restrict__ Of, int K) {
  constexpr int LDK = 40;  // 32 + 8 pad, keeps 16B alignment, breaks pow2 bank stride
  __shared__ __align__(16) u16 As[128 * LDK];
  __shared__ __align__(16) u16 Bs[128 * LDK];
  int mt = blockIdx.x, nt = blockIdx.y;
  int tid = threadIdx.x;
  int wid = tid >> 6, lane = tid & 63;
  int lr = lane & 15, lg = lane >> 4;
  int mw = (wid >> 1) * 64, nw = (wid & 1) * 64;
  int arow = tid >> 1, acol = (tid & 1) * 16;
  const long aBase = (long)(mt * 128 + arow) * K + acol;
  const long bBase = (long)(nt * 128 + arow) * K + acol;
  f32x4 acc[4][4] = {};
  for (int k0 = 0; k0 < K; k0 += 32) {
    short8 av0 = *(const short8*)(A + aBase + k0);
    short8 av1 = *(const short8*)(A + aBase + k0 + 8);
    short8 bv0 = *(const short8*)(Bt + bBase + k0);
    short8 bv1 = *(const short8*)(Bt + bBase + k0 + 8);
    __syncthreads();
    *(short8*)(As + arow * LDK + acol)     = av0;
    *(short8*)(As + arow * LDK + acol + 8) = av1;
    *(short8*)(Bs + arow * LDK + acol)     = bv0;
    *(short8*)(Bs + arow * LDK + acol + 8) = bv1;
    __syncthreads();
    short8 af[4], bf[4];
    #pragma unroll
    for (int i = 0; i < 4; i++)
      af[i] = *(const short8*)(As + (mw + i * 16 + lr) * LDK + lg * 8);
    #pragma unroll
    for (int i = 0; i < 4; i++)
      bf[i] = *(const short8*)(Bs + (nw + i * 16 + lr) * LDK + lg * 8);
    #pragma unroll
    for (int i = 0; i < 4; i++)
      #pragma unroll
      for (int j = 0; j < 4; j++)
        acc[i][j] = __builtin_amdgcn_mfma_f32_16x16x32_bf16(af[i], bf[j], acc[i][j], 0, 0, 0);
  }
  #pragma unroll
  for (int i = 0; i < 4; i++) {
    #pragma unroll
    for (int j = 0; j < 4; j++) {
      int mbase = mt * 128 + mw + i * 16 + lg * 4;      // C/D: row=(lane>>4)*4+r
      int n     = nt * 128 + nw + j * 16 + lr;          //      col=lane&15
      #pragma unroll
      for (int r = 0; r < 4; r++) {
        float val = acc[i][j][r];
        int m = mbase + r;
        if (MODE == 0) {
          int b = m >> 11, t = m & (T_ - 1);
          int h = n / 192, f = n % 192;
          long o = (((long)(b * H_ + h)) * T_ + t) * HS_;
          if (f < 64)       Oq[o + f]       = f2bf(val * 0.03125f);  // fold C^-0.5
          else if (f < 128) Ok[o + f - 64]  = f2bf(val);
          else              Ov[o + f - 128] = f2bf(val);
        } else {
          Of[(long)m * D_ + n] = val;
        }
      }
    }
  }
}

// -------- transpose V [bh][T][64] -> Vt [bh][64][T]  +  per-tile column sums --------
__global__ void k_transpose_v(const u16* __restrict__ V, u16* __restrict__ Vt,
                              float* __restrict__ Partial) {
  __shared__ u16 tile[64][65];
  __shared__ float psum[4][64];
  int bh = blockIdx.z;
  int jt = blockIdx.x;          // tile index
  int t0 = jt * 64;
  int tx = threadIdx.x & 63, ty = threadIdx.x >> 6;
  const u16* src = V + (long)bh * T_ * HS_;
  u16* dst = Vt + (long)bh * T_ * HS_;
  #pragma unroll
  for (int i = 0; i < 64; i += 4)
    tile[ty + i][tx] = src[(long)(t0 + ty + i) * HS_ + tx];
  __syncthreads();
  #pragma unroll
  for (int i = 0; i < 64; i += 4)
    dst[(long)(ty + i) * T_ + t0 + tx] = tile[tx][ty + i];
  // per-tile column sums: thread (ty,tx) sums 16 rows of dim tx
  float s = 0.f;
  #pragma unroll
  for (int i = 0; i < 16; i++)
    s += bf2f(tile[ty * 16 + i][tx]);
  psum[ty][tx] = s;
  __syncthreads();
  if (threadIdx.x < 64)
    Partial[((long)bh * NTILE_ + jt) * HS_ + threadIdx.x] =
        psum[0][threadIdx.x] + psum[1][threadIdx.x] + psum[2][threadIdx.x] + psum[3][threadIdx.x];
}

// -------- suffix scan over tile sums: Suf[bh][j][d] = sum_{jt >= j} Partial[bh][jt][d] --------
__global__ void k_vscan(const float* __restrict__ Partial, float* __restrict__ Suf) {
  int bh = blockIdx.x;
  int d = threadIdx.x;
  const float* Pb = Partial + (long)bh * NTILE_ * HS_;
  float* Sb = Suf + (long)bh * (NTILE_ + 1) * HS_;
  float acc = 0.f;
  Sb[NTILE_ * HS_ + d] = 0.f;
  for (int j = NTILE_ - 1; j >= 0; j--) {
    acc += Pb[j * HS_ + d];
    Sb[j * HS_ + d] = acc;
  }
}

// ---------------- fused attention: causal tiles + closed-form masked-suffix correction ----------------
// Work-balanced: block x handles qt = x AND qt = NTILE-1-x  => exactly NTILE+1 tile-iters per block.
__global__ __launch_bounds__(256) void k_attn(
    const u16* __restrict__ Q, const u16* __restrict__ Kc,
    const u16* __restrict__ Vt, const float* __restrict__ Suf,
    u16* __restrict__ Mha) {
  __shared__ __align__(16) u16 Ks[64 * 72];
  __shared__ __align__(16) u16 Vs[64 * 72];
  __shared__ __align__(16) u16 Ps[4][16 * 72];
  int bh = blockIdx.y;
  int b = bh >> 4, h = bh & 15;
  int tid = threadIdx.x, wid = tid >> 6, lane = tid & 63;
  int lr = lane & 15, lg = lane >> 4;
  const u16* Qb = Q  + (long)bh * T_ * HS_;
  const u16* Kb = Kc + (long)bh * T_ * HS_;
  const u16* Vb = Vt + (long)bh * T_ * HS_;   // [64][T]
  int srow = tid >> 2, scol = (tid & 3) * 16;

  #pragma unroll 1
  for (int half = 0; half < 2; half++) {
    int qt = half ? (NTILE_ - 1 - (int)blockIdx.x) : (int)blockIdx.x;
    int qrow = qt * 64 + wid * 16 + lr;         // A-operand: m = lane&15
    short8 qf0 = *(const short8*)(Qb + (long)qrow * HS_ + lg * 8);
    short8 qf1 = *(const short8*)(Qb + (long)qrow * HS_ + 32 + lg * 8);
    f32x4 accO[4] = {};                         // rows lg*4+r, cols fd*16+lr
    float mrun[4], lpart[4];
    #pragma unroll
    for (int r = 0; r < 4; r++) { mrun[r] = 1e-9f; lpart[r] = 0.f; }  // init covers masked max
    const int jend = qt * 64;
    for (int j0 = 0; j0 <= jend; j0 += 64) {
      const bool diag = (j0 == jend);
      __syncthreads();
      *(short8*)(Ks + srow * 72 + scol)     = *(const short8*)(Kb + (long)(j0 + srow) * HS_ + scol);
      *(short8*)(Ks + srow * 72 + scol + 8) = *(const short8*)(Kb + (long)(j0 + srow) * HS_ + scol + 8);
      *(short8*)(Vs + srow * 72 + scol)     = *(const short8*)(Vb + (long)srow * T_ + j0 + scol);
      *(short8*)(Vs + srow * 72 + scol + 8) = *(const short8*)(Vb + (long)srow * T_ + j0 + scol + 8);
      __syncthreads();
      // S = Q K^T  (scale already folded into Q)
      f32x4 s4[4];
      #pragma unroll
      for (int fn = 0; fn < 4; fn++) {
        short8 kb0 = *(const short8*)(Ks + (fn * 16 + lr) * 72 + lg * 8);
        short8 kb1 = *(const short8*)(Ks + (fn * 16 + lr) * 72 + 32 + lg * 8);
        f32x4 z = {};
        z = __builtin_amdgcn_mfma_f32_16x16x32_bf16(qf0, kb0, z, 0, 0, 0);
        z = __builtin_amdgcn_mfma_f32_16x16x32_bf16(qf1, kb1, z, 0, 0, 0);
        s4[fn] = z;
      }
      // online softmax; m-reduce over lr (4-step shfl); l kept as per-lane partial
      float scl[4];
      float pv[4][4];
      #pragma unroll
      for (int r = 0; r < 4; r++) {
        float vals[4];
        if (diag) {
          int trow = qt * 64 + wid * 16 + lg * 4 + r;
          #pragma unroll
          for (int fn = 0; fn < 4; fn++) {
            int s = j0 + fn * 16 + lr;
            vals[fn] = (s <= trow) ? s4[fn][r] : 1e-9f;   // faithful masked_fill(1e-9)
          }
        } else {
          #pragma unroll
          for (int fn = 0; fn < 4; fn++) vals[fn] = s4[fn][r];
        }
        float tmax = fmaxf(fmaxf(vals[0], vals[1]), fmaxf(vals[2], vals[3]));
        #pragma unroll
        for (int sh = 1; sh < 16; sh <<= 1)
          tmax = fmaxf(tmax, __shfl_xor(tmax, sh, 64));
        float mn = fmaxf(mrun[r], tmax);
        scl[r] = __expf(mrun[r] - mn);
        mrun[r] = mn;
        float psum = 0.f;
        #pragma unroll
        for (int fn = 0; fn < 4; fn++) {
          float pe = __expf(vals[fn] - mn);
          pv[fn][r] = pe;
          psum += pe;
        }
        lpart[r] = lpart[r] * scl[r] + psum;   // per-lane partial; reduced once at end
      }
      #pragma unroll
      for (int fd = 0; fd < 4; fd++)
        #pragma unroll
        for (int r = 0; r < 4; r++)
          accO[fd][r] *= scl[r];
      // P: D-layout -> A-layout via per-wave LDS bounce
      #pragma unroll
      for (int fn = 0; fn < 4; fn++)
        #pragma unroll
        for (int r = 0; r < 4; r++)
          Ps[wid][(lg * 4 + r) * 72 + fn * 16 + lr] = f2bf(pv[fn][r]);
      short8 pa0 = *(const short8*)(&Ps[wid][lr * 72 + lg * 8]);
      short8 pa1 = *(const short8*)(&Ps[wid][lr * 72 + 32 + lg * 8]);
      #pragma unroll
      for (int fd = 0; fd < 4; fd++) {
        short8 vb0 = *(const short8*)(Vs + (fd * 16 + lr) * 72 + lg * 8);
        short8 vb1 = *(const short8*)(Vs + (fd * 16 + lr) * 72 + 32 + lg * 8);
        accO[fd] = __builtin_amdgcn_mfma_f32_16x16x32_bf16(pa0, vb0, accO[fd], 0, 0, 0);
        accO[fd] = __builtin_amdgcn_mfma_f32_16x16x32_bf16(pa1, vb1, accO[fd], 0, 0, 0);
      }
    }
    // full l reduce (deferred), then closed-form masked-suffix correction
    float lrun[4];
    #pragma unroll
    for (int r = 0; r < 4; r++) {
      float ps = lpart[r];
      #pragma unroll
      for (int sh = 1; sh < 16; sh <<= 1)
        ps += __shfl_xor(ps, sh, 64);
      lrun[r] = ps;
    }
    {
      int nmask = T_ - (qt + 1) * 64;
      const float* sufp = Suf + ((long)bh * (NTILE_ + 1) + (qt + 1)) * HS_;
      float sufv[4];
      #pragma unroll
      for (int fd = 0; fd < 4; fd++) sufv[fd] = sufp[fd * 16 + lr];
      #pragma unroll
      for (int r = 0; r < 4; r++) {
        float pm = __expf(1e-9f - mrun[r]);
        lrun[r] += (float)nmask * pm;
        #pragma unroll
        for (int fd = 0; fd < 4; fd++)
          accO[fd][r] += pm * sufv[fd];
      }
    }
    #pragma unroll
    for (int fd = 0; fd < 4; fd++) {
      #pragma unroll
      for (int r = 0; r < 4; r++) {
        int trow = qt * 64 + wid * 16 + lg * 4 + r;
        int dcol = fd * 16 + lr;
        float o = accO[fd][r] / lrun[r];
        Mha[((long)(b * T_ + trow)) * D_ + h * HS_ + dcol] = f2bf(o);
      }
    }
    __syncthreads();
  }
}

extern "C" void kernel_launch(void* const* d_in, const int* in_sizes, int n_in,
                              void* d_out, int out_size, void* d_ws, size_t ws_size,
                              hipStream_t stream) {
  const float* x    = (const float*)d_in[0];
  const float* wqkv = (const float*)d_in[1];   // [16][1024][192]
  const float* wout = (const float*)d_in[2];   // [1024][1024]
  float* out = (float*)d_out;

  char* p = (char*)d_ws;
  u16* Xb    = (u16*)p; p += (size_t)M_ * D_ * 2;        // x as bf16 [8192][1024]
  u16* WqkvT = (u16*)p; p += (size_t)NQKV_ * D_ * 2;     // [3072][1024]  (n-major, k-contig)
  u16* WoutT = (u16*)p; p += (size_t)D_ * D_ * 2;        // [1024][1024]  W_out^T
  u16* Qw  = (u16*)p; p += (size_t)B_ * H_ * T_ * HS_ * 2;  // [B,H,T,64], pre-scaled
  u16* Kw  = (u16*)p; p += (size_t)B_ * H_ * T_ * HS_ * 2;
  u16* Vw  = (u16*)p; p += (size_t)B_ * H_ * T_ * HS_ * 2;
  u16* Vtw = (u16*)p; p += (size_t)B_ * H_ * T_ * HS_ * 2;  // [B,H,64,T]
  u16* Mha = (u16*)p; p += (size_t)M_ * D_ * 2;             // [8192][1024]
  float* Suf = (float*)p; p += (size_t)B_ * H_ * (NTILE_ + 1) * HS_ * 4;  // [bh][33][64] fp32
  float* Part = (float*)p; p += (size_t)B_ * H_ * NTILE_ * HS_ * 4;       // [bh][32][64] fp32

  k_cvt_x<<<dim3(M_ * D_ / 4 / 256), dim3(256), 0, stream>>>(x, Xb, M_ * D_ / 4);
  k_transpose_cvt<<<dim3(192 / 32, D_ / 32, H_), dim3(32, 8), 0, stream>>>(
      wqkv, WqkvT, D_, 192, (long)D_ * 192, (long)192 * D_);
  k_transpose_cvt<<<dim3(D_ / 32, D_ / 32, 1), dim3(32, 8), 0, stream>>>(
      wout, WoutT, D_, D_, 0, 0);
  k_gemm<0><<<dim3(M_ / 128, NQKV_ / 128), dim3(256), 0, stream>>>(
      Xb, WqkvT, Qw, Kw, Vw, nullptr, D_);
  k_transpose_v<<<dim3(T_ / 64, 1, B_ * H_), dim3(256), 0, stream>>>(Vw, Vtw, Part);
  k_vscan<<<dim3(B_ * H_), dim3(64), 0, stream>>>(Part, Suf);
  k_attn<<<dim3(NTILE_ / 2, B_ * H_), dim3(256), 0, stream>>>(Qw, Kw, Vtw, Suf, Mha);
  k_gemm<1><<<dim3(M_ / 128, D_ / 128), dim3(256), 0, stream>>>(
      Mha, WoutT, nullptr, nullptr, nullptr, out, D_);
}

// Round 5
// 240.141 us; speedup vs baseline: 1.7854x; 1.1387x over previous
//
#include <hip/hip_runtime.h>

typedef unsigned short u16;
typedef __attribute__((ext_vector_type(8))) short short8;   // 8 x bf16 (4 VGPRs)
typedef __attribute__((ext_vector_type(4))) short short4v;
typedef __attribute__((ext_vector_type(4))) float f32x4;

#define B_  4
#define T_  2048
#define D_  1024
#define H_  16
#define HS_ 64
#define M_    (B_ * T_)        /* 8192 */
#define NQKV_ (H_ * 3 * HS_)   /* 3072 */
#define NTILE_ (T_ / 64)       /* 32 */
#define LOG2E_ 1.44269504088896340736f

__device__ __forceinline__ u16 f2bf(float f) {
  union { float f; unsigned u; } v; v.f = f;
  unsigned u = v.u;
  return (u16)((u + 0x7FFFu + ((u >> 16) & 1u)) >> 16);  // RNE
}
__device__ __forceinline__ float bf2f(u16 h) {
  union { unsigned u; float f; } v; v.u = ((unsigned)h) << 16; return v.f;
}
__device__ __forceinline__ void gload16(const u16* g, u16* l) {
  __builtin_amdgcn_global_load_lds(
      (const __attribute__((address_space(1))) void*)g,
      (__attribute__((address_space(3))) void*)l, 16, 0, 0);
}

// ---------------- convert x (fp32) -> bf16 ----------------
__global__ void k_cvt_x(const float* __restrict__ x, u16* __restrict__ o, int n4) {
  int i = blockIdx.x * 256 + threadIdx.x;
  if (i < n4) {
    float4 v = ((const float4*)x)[i];
    short4v d;
    d[0] = (short)f2bf(v.x); d[1] = (short)f2bf(v.y);
    d[2] = (short)f2bf(v.z); d[3] = (short)f2bf(v.w);
    ((short4v*)o)[i] = d;
  }
}

// ------- transpose+convert: in fp32 [R][C] (+h*sIn) -> out bf16 [C][R] (+h*sOut) -------
__global__ void k_transpose_cvt(const float* __restrict__ in, u16* __restrict__ out,
                                int R, int C, long sIn, long sOut) {
  __shared__ float tile[32][33];
  int h = blockIdx.z;
  const float* src = in + (long)h * sIn;
  u16* dst = out + (long)h * sOut;
  int r0 = blockIdx.y * 32, c0 = blockIdx.x * 32;
  int tx = threadIdx.x, ty = threadIdx.y;  // 32 x 8
  #pragma unroll
  for (int i = 0; i < 32; i += 8) {
    int r = r0 + ty + i, c = c0 + tx;
    tile[ty + i][tx] = (r < R && c < C) ? src[(long)r * C + c] : 0.f;
  }
  __syncthreads();
  #pragma unroll
  for (int i = 0; i < 32; i += 8) {
    int c = c0 + ty + i, r = r0 + tx;
    if (c < C && r < R) dst[(long)c * R + r] = f2bf(tile[tx][ty + i]);
  }
}

// ---------------- GEMM: C[M][N] = A[M][K] @ Bt[N][K]^T (bf16 in, fp32 acc) ----------------
// global_load_lds width-16 staging into linear [128][32] LDS tiles (m97 pattern).
// MODE 0: scatter epilogue -> Q(*log2e/32), K, V  [B,H,T,64] bf16.  MODE 1: fp32 row-major out.
template<int MODE>
__global__ __launch_bounds__(256) void k_gemm(
    const u16* __restrict__ A, const u16* __restrict__ Bt,
    u16* __restrict__ Oq, u16* __restrict__ Ok, u16* __restrict__ Ov,
    float* __restrict__ Of, int K) {
  __shared__ __align__(16) u16 As[128 * 32];
  __shared__ __align__(16) u16 Bs[128 * 32];
  int mt = blockIdx.x, nt = blockIdx.y;
  int tid = threadIdx.x;
  int wid = tid >> 6, lane = tid & 63;
  int lr = lane & 15, lg = lane >> 4;
  int mw = (wid >> 1) * 64, nw = (wid & 1) * 64;
  // staging: 512 16B-chunks per matrix; wave w covers chunks [w*128, w*128+128)
  int c0chunk = wid * 128 + lane;          // +0 and +64
  int row0 = c0chunk >> 2,      q0 = c0chunk & 3;
  int row1 = (c0chunk + 64) >> 2, q1 = (c0chunk + 64) & 3;
  const u16* Arow0 = A  + (long)(mt * 128 + row0) * K + q0 * 8;
  const u16* Arow1 = A  + (long)(mt * 128 + row1) * K + q1 * 8;
  const u16* Brow0 = Bt + (long)(nt * 128 + row0) * K + q0 * 8;
  const u16* Brow1 = Bt + (long)(nt * 128 + row1) * K + q1 * 8;
  u16* ldsA0 = As + (wid * 128) * 8;       // wave-uniform LDS base (lane*16B implicit)
  u16* ldsA1 = As + (wid * 128 + 64) * 8;
  u16* ldsB0 = Bs + (wid * 128) * 8;
  u16* ldsB1 = Bs + (wid * 128 + 64) * 8;
  f32x4 acc[4][4] = {};
  for (int k0 = 0; k0 < K; k0 += 32) {
    __syncthreads();   // prior iter's LDS reads done
    gload16(Arow0 + k0, ldsA0);
    gload16(Arow1 + k0, ldsA1);
    gload16(Brow0 + k0, ldsB0);
    gload16(Brow1 + k0, ldsB1);
    __syncthreads();   // staging complete (compiler emits vmcnt(0) before barrier)
    short8 af[4], bf[4];
    #pragma unroll
    for (int i = 0; i < 4; i++)
      af[i] = *(const short8*)(As + (mw + i * 16 + lr) * 32 + lg * 8);
    #pragma unroll
    for (int i = 0; i < 4; i++)
      bf[i] = *(const short8*)(Bs + (nw + i * 16 + lr) * 32 + lg * 8);
    #pragma unroll
    for (int i = 0; i < 4; i++)
      #pragma unroll
      for (int j = 0; j < 4; j++)
        acc[i][j] = __builtin_amdgcn_mfma_f32_16x16x32_bf16(af[i], bf[j], acc[i][j], 0, 0, 0);
  }
  #pragma unroll
  for (int i = 0; i < 4; i++) {
    #pragma unroll
    for (int j = 0; j < 4; j++) {
      int mbase = mt * 128 + mw + i * 16 + lg * 4;      // C/D: row=(lane>>4)*4+r
      int n     = nt * 128 + nw + j * 16 + lr;          //      col=lane&15
      #pragma unroll
      for (int r = 0; r < 4; r++) {
        float val = acc[i][j][r];
        int m = mbase + r;
        if (MODE == 0) {
          int b = m >> 11, t = m & (T_ - 1);
          int h = n / 192, f = n % 192;
          long o = (((long)(b * H_ + h)) * T_ + t) * HS_;
          if (f < 64)       Oq[o + f]       = f2bf(val * (0.03125f * LOG2E_));  // fold C^-0.5 * log2e
          else if (f < 128) Ok[o + f - 64]  = f2bf(val);
          else              Ov[o + f - 128] = f2bf(val);
        } else {
          Of[(long)m * D_ + n] = val;
        }
      }
    }
  }
}

// -------- transpose V [bh][T][64] -> Vt [bh][64][T]  +  per-tile column sums --------
__global__ void k_transpose_v(const u16* __restrict__ V, u16* __restrict__ Vt,
                              float* __restrict__ Partial) {
  __shared__ u16 tile[64][65];
  __shared__ float psum[4][64];
  int bh = blockIdx.z;
  int jt = blockIdx.x;          // tile index
  int t0 = jt * 64;
  int tx = threadIdx.x & 63, ty = threadIdx.x >> 6;
  const u16* src = V + (long)bh * T_ * HS_;
  u16* dst = Vt + (long)bh * T_ * HS_;
  #pragma unroll
  for (int i = 0; i < 64; i += 4)
    tile[ty + i][tx] = src[(long)(t0 + ty + i) * HS_ + tx];
  __syncthreads();
  #pragma unroll
  for (int i = 0; i < 64; i += 4)
    dst[(long)(ty + i) * T_ + t0 + tx] = tile[tx][ty + i];
  // per-tile column sums: thread (ty,tx) sums 16 rows of dim tx
  float s = 0.f;
  #pragma unroll
  for (int i = 0; i < 16; i++)
    s += bf2f(tile[ty * 16 + i][tx]);
  psum[ty][tx] = s;
  __syncthreads();
  if (threadIdx.x < 64)
    Partial[((long)bh * NTILE_ + jt) * HS_ + threadIdx.x] =
        psum[0][threadIdx.x] + psum[1][threadIdx.x] + psum[2][threadIdx.x] + psum[3][threadIdx.x];
}

// -------- suffix scan over tile sums: Suf[bh][j][d] = sum_{jt >= j} Partial[bh][jt][d] --------
__global__ void k_vscan(const float* __restrict__ Partial, float* __restrict__ Suf) {
  int bh = blockIdx.x;
  int d = threadIdx.x;
  const float* Pb = Partial + (long)bh * NTILE_ * HS_;
  float* Sb = Suf + (long)bh * (NTILE_ + 1) * HS_;
  float acc = 0.f;
  Sb[NTILE_ * HS_ + d] = 0.f;
  for (int j = NTILE_ - 1; j >= 0; j--) {
    acc += Pb[j * HS_ + d];
    Sb[j * HS_ + d] = acc;
  }
}

// ---------------- fused attention: causal tiles + closed-form masked-suffix correction ----------------
// No-max softmax: scores*log2e pre-folded into Q; P = exp2(s2); masked entries P = 1.0 exactly.
// Work-balanced: block x handles qt = x AND qt = NTILE-1-x  => exactly NTILE+1 tile-iters per block.
__global__ __launch_bounds__(256) void k_attn(
    const u16* __restrict__ Q, const u16* __restrict__ Kc,
    const u16* __restrict__ Vt, const float* __restrict__ Suf,
    u16* __restrict__ Mha) {
  __shared__ __align__(16) u16 Ks[64 * 72];
  __shared__ __align__(16) u16 Vs[64 * 72];
  __shared__ __align__(16) u16 Ps[4][16 * 72];
  int bh = blockIdx.y;
  int b = bh >> 4, h = bh & 15;
  int tid = threadIdx.x, wid = tid >> 6, lane = tid & 63;
  int lr = lane & 15, lg = lane >> 4;
  const u16* Qb = Q  + (long)bh * T_ * HS_;
  const u16* Kb = Kc + (long)bh * T_ * HS_;
  const u16* Vb = Vt + (long)bh * T_ * HS_;   // [64][T]
  int srow = tid >> 2, scol = (tid & 3) * 16;

  #pragma unroll 1
  for (int half = 0; half < 2; half++) {
    int qt = half ? (NTILE_ - 1 - (int)blockIdx.x) : (int)blockIdx.x;
    int qrow = qt * 64 + wid * 16 + lr;         // A-operand: m = lane&15
    short8 qf0 = *(const short8*)(Qb + (long)qrow * HS_ + lg * 8);
    short8 qf1 = *(const short8*)(Qb + (long)qrow * HS_ + 32 + lg * 8);
    f32x4 accO[4] = {};                         // rows lg*4+r, cols fd*16+lr
    float lpart[4] = {0.f, 0.f, 0.f, 0.f};
    const int jend = qt * 64;
    for (int j0 = 0; j0 <= jend; j0 += 64) {
      const bool diag = (j0 == jend);
      __syncthreads();
      *(short8*)(Ks + srow * 72 + scol)     = *(const short8*)(Kb + (long)(j0 + srow) * HS_ + scol);
      *(short8*)(Ks + srow * 72 + scol + 8) = *(const short8*)(Kb + (long)(j0 + srow) * HS_ + scol + 8);
      *(short8*)(Vs + srow * 72 + scol)     = *(const short8*)(Vb + (long)srow * T_ + j0 + scol);
      *(short8*)(Vs + srow * 72 + scol + 8) = *(const short8*)(Vb + (long)srow * T_ + j0 + scol + 8);
      __syncthreads();
      // S2 = Q K^T  (scale * log2e already folded into Q)
      f32x4 s4[4];
      #pragma unroll
      for (int fn = 0; fn < 4; fn++) {
        short8 kb0 = *(const short8*)(Ks + (fn * 16 + lr) * 72 + lg * 8);
        short8 kb1 = *(const short8*)(Ks + (fn * 16 + lr) * 72 + 32 + lg * 8);
        f32x4 z = {};
        z = __builtin_amdgcn_mfma_f32_16x16x32_bf16(qf0, kb0, z, 0, 0, 0);
        z = __builtin_amdgcn_mfma_f32_16x16x32_bf16(qf1, kb1, z, 0, 0, 0);
        s4[fn] = z;
      }
      // no-max softmax: P = exp2(s2); masked -> exp2(0) = 1.0 (== exp(1e-9) in fp32)
      float pv[4][4];
      #pragma unroll
      for (int r = 0; r < 4; r++) {
        float vals[4];
        if (diag) {
          int trow = qt * 64 + wid * 16 + lg * 4 + r;
          #pragma unroll
          for (int fn = 0; fn < 4; fn++) {
            int s = j0 + fn * 16 + lr;
            vals[fn] = (s <= trow) ? s4[fn][r] : 0.0f;   // faithful masked_fill(1e-9)
          }
        } else {
          #pragma unroll
          for (int fn = 0; fn < 4; fn++) vals[fn] = s4[fn][r];
        }
        float psum = 0.f;
        #pragma unroll
        for (int fn = 0; fn < 4; fn++) {
          float pe = exp2f(vals[fn]);
          pv[fn][r] = pe;
          psum += pe;
        }
        lpart[r] += psum;   // per-lane partial; reduced once at end
      }
      // P: D-layout -> A-layout via per-wave LDS bounce
      #pragma unroll
      for (int fn = 0; fn < 4; fn++)
        #pragma unroll
        for (int r = 0; r < 4; r++)
          Ps[wid][(lg * 4 + r) * 72 + fn * 16 + lr] = f2bf(pv[fn][r]);
      short8 pa0 = *(const short8*)(&Ps[wid][lr * 72 + lg * 8]);
      short8 pa1 = *(const short8*)(&Ps[wid][lr * 72 + 32 + lg * 8]);
      #pragma unroll
      for (int fd = 0; fd < 4; fd++) {
        short8 vb0 = *(const short8*)(Vs + (fd * 16 + lr) * 72 + lg * 8);
        short8 vb1 = *(const short8*)(Vs + (fd * 16 + lr) * 72 + 32 + lg * 8);
        accO[fd] = __builtin_amdgcn_mfma_f32_16x16x32_bf16(pa0, vb0, accO[fd], 0, 0, 0);
        accO[fd] = __builtin_amdgcn_mfma_f32_16x16x32_bf16(pa1, vb1, accO[fd], 0, 0, 0);
      }
    }
    // full l reduce (deferred), then closed-form masked-suffix correction (pm = exp(1e-9) = 1.0)
    float lrun[4];
    #pragma unroll
    for (int r = 0; r < 4; r++) {
      float ps = lpart[r];
      #pragma unroll
      for (int sh = 1; sh < 16; sh <<= 1)
        ps += __shfl_xor(ps, sh, 64);
      lrun[r] = ps;
    }
    {
      int nmask = T_ - (qt + 1) * 64;
      const float* sufp = Suf + ((long)bh * (NTILE_ + 1) + (qt + 1)) * HS_;
      float sufv[4];
      #pragma unroll
      for (int fd = 0; fd < 4; fd++) sufv[fd] = sufp[fd * 16 + lr];
      #pragma unroll
      for (int r = 0; r < 4; r++) {
        lrun[r] += (float)nmask;
        #pragma unroll
        for (int fd = 0; fd < 4; fd++)
          accO[fd][r] += sufv[fd];
      }
    }
    #pragma unroll
    for (int fd = 0; fd < 4; fd++) {
      #pragma unroll
      for (int r = 0; r < 4; r++) {
        int trow = qt * 64 + wid * 16 + lg * 4 + r;
        int dcol = fd * 16 + lr;
        float o = accO[fd][r] / lrun[r];
        Mha[((long)(b * T_ + trow)) * D_ + h * HS_ + dcol] = f2bf(o);
      }
    }
    __syncthreads();
  }
}

extern "C" void kernel_launch(void* const* d_in, const int* in_sizes, int n_in,
                              void* d_out, int out_size, void* d_ws, size_t ws_size,
                              hipStream_t stream) {
  const float* x    = (const float*)d_in[0];
  const float* wqkv = (const float*)d_in[1];   // [16][1024][192]
  const float* wout = (const float*)d_in[2];   // [1024][1024]
  float* out = (float*)d_out;

  char* p = (char*)d_ws;
  u16* Xb    = (u16*)p; p += (size_t)M_ * D_ * 2;        // x as bf16 [8192][1024]
  u16* WqkvT = (u16*)p; p += (size_t)NQKV_ * D_ * 2;     // [3072][1024]  (n-major, k-contig)
  u16* WoutT = (u16*)p; p += (size_t)D_ * D_ * 2;        // [1024][1024]  W_out^T
  u16* Qw  = (u16*)p; p += (size_t)B_ * H_ * T_ * HS_ * 2;  // [B,H,T,64], pre-scaled by C^-0.5*log2e
  u16* Kw  = (u16*)p; p += (size_t)B_ * H_ * T_ * HS_ * 2;
  u16* Vw  = (u16*)p; p += (size_t)B_ * H_ * T_ * HS_ * 2;
  u16* Vtw = (u16*)p; p += (size_t)B_ * H_ * T_ * HS_ * 2;  // [B,H,64,T]
  u16* Mha = (u16*)p; p += (size_t)M_ * D_ * 2;             // [8192][1024]
  float* Suf = (float*)p; p += (size_t)B_ * H_ * (NTILE_ + 1) * HS_ * 4;  // [bh][33][64] fp32
  float* Part = (float*)p; p += (size_t)B_ * H_ * NTILE_ * HS_ * 4;       // [bh][32][64] fp32

  k_cvt_x<<<dim3(M_ * D_ / 4 / 256), dim3(256), 0, stream>>>(x, Xb, M_ * D_ / 4);
  k_transpose_cvt<<<dim3(192 / 32, D_ / 32, H_), dim3(32, 8), 0, stream>>>(
      wqkv, WqkvT, D_, 192, (long)D_ * 192, (long)192 * D_);
  k_transpose_cvt<<<dim3(D_ / 32, D_ / 32, 1), dim3(32, 8), 0, stream>>>(
      wout, WoutT, D_, D_, 0, 0);
  k_gemm<0><<<dim3(M_ / 128, NQKV_ / 128), dim3(256), 0, stream>>>(
      Xb, WqkvT, Qw, Kw, Vw, nullptr, D_);
  k_transpose_v<<<dim3(T_ / 64, 1, B_ * H_), dim3(256), 0, stream>>>(Vw, Vtw, Part);
  k_vscan<<<dim3(B_ * H_), dim3(64), 0, stream>>>(Part, Suf);
  k_attn<<<dim3(NTILE_ / 2, B_ * H_), dim3(256), 0, stream>>>(Qw, Kw, Vtw, Suf, Mha);
  k_gemm<1><<<dim3(M_ / 128, D_ / 128), dim3(256), 0, stream>>>(
      Mha, WoutT, nullptr, nullptr, nullptr, out, D_);
}

// Round 6
// 224.125 us; speedup vs baseline: 1.9130x; 1.0715x over previous
//
#include <hip/hip_runtime.h>

typedef unsigned short u16;
typedef __attribute__((ext_vector_type(8))) short short8;   // 8 x bf16 (4 VGPRs)
typedef __attribute__((ext_vector_type(4))) short short4v;
typedef __attribute__((ext_vector_type(4))) float f32x4;

#define B_  4
#define T_  2048
#define D_  1024
#define H_  16
#define HS_ 64
#define M_    (B_ * T_)        /* 8192 */
#define NQKV_ (H_ * 3 * HS_)   /* 3072 */
#define NTILE_ (T_ / 64)       /* 32 */
#define LOG2E_ 1.44269504088896340736f

__device__ __forceinline__ u16 f2bf(float f) {
  union { float f; unsigned u; } v; v.f = f;
  unsigned u = v.u;
  return (u16)((u + 0x7FFFu + ((u >> 16) & 1u)) >> 16);  // RNE
}
__device__ __forceinline__ float bf2f(u16 h) {
  union { unsigned u; float f; } v; v.u = ((unsigned)h) << 16; return v.f;
}
__device__ __forceinline__ unsigned pkbf(float lo, float hi) {
  unsigned r;
  asm("v_cvt_pk_bf16_f32 %0, %1, %2" : "=v"(r) : "v"(lo), "v"(hi));
  return r;
}
__device__ __forceinline__ void gload16(const u16* g, u16* l) {
  __builtin_amdgcn_global_load_lds(
      (const __attribute__((address_space(1))) void*)g,
      (__attribute__((address_space(3))) void*)l, 16, 0, 0);
}

// ---------------- convert x (fp32) -> bf16 ----------------
__global__ void k_cvt_x(const float* __restrict__ x, u16* __restrict__ o, int n4) {
  int i = blockIdx.x * 256 + threadIdx.x;
  if (i < n4) {
    float4 v = ((const float4*)x)[i];
    short4v d;
    d[0] = (short)f2bf(v.x); d[1] = (short)f2bf(v.y);
    d[2] = (short)f2bf(v.z); d[3] = (short)f2bf(v.w);
    ((short4v*)o)[i] = d;
  }
}

// ------- transpose+convert: in fp32 [R][C] (+h*sIn) -> out bf16 [C][R] (+h*sOut) -------
__global__ void k_transpose_cvt(const float* __restrict__ in, u16* __restrict__ out,
                                int R, int C, long sIn, long sOut) {
  __shared__ float tile[32][33];
  int h = blockIdx.z;
  const float* src = in + (long)h * sIn;
  u16* dst = out + (long)h * sOut;
  int r0 = blockIdx.y * 32, c0 = blockIdx.x * 32;
  int tx = threadIdx.x, ty = threadIdx.y;  // 32 x 8
  #pragma unroll
  for (int i = 0; i < 32; i += 8) {
    int r = r0 + ty + i, c = c0 + tx;
    tile[ty + i][tx] = (r < R && c < C) ? src[(long)r * C + c] : 0.f;
  }
  __syncthreads();
  #pragma unroll
  for (int i = 0; i < 32; i += 8) {
    int c = c0 + ty + i, r = r0 + tx;
    if (c < C && r < R) dst[(long)c * R + r] = f2bf(tile[tx][ty + i]);
  }
}

// ---------------- GEMM: C[M][N] = A[M][K] @ Bt[N][K]^T (bf16 in, fp32 acc) ----------------
// global_load_lds width-16 staging into linear [128][32] LDS tiles (m97 pattern).
// MODE 0: scatter epilogue -> Q(*log2e/32), K, V  [B,H,T,64] bf16.  MODE 1: fp32 row-major out.
template<int MODE>
__global__ __launch_bounds__(256) void k_gemm(
    const u16* __restrict__ A, const u16* __restrict__ Bt,
    u16* __restrict__ Oq, u16* __restrict__ Ok, u16* __restrict__ Ov,
    float* __restrict__ Of, int K) {
  __shared__ __align__(16) u16 As[128 * 32];
  __shared__ __align__(16) u16 Bs[128 * 32];
  int mt = blockIdx.x, nt = blockIdx.y;
  int tid = threadIdx.x;
  int wid = tid >> 6, lane = tid & 63;
  int lr = lane & 15, lg = lane >> 4;
  int mw = (wid >> 1) * 64, nw = (wid & 1) * 64;
  // staging: 512 16B-chunks per matrix; wave w covers chunks [w*128, w*128+128)
  int c0chunk = wid * 128 + lane;          // +0 and +64
  int row0 = c0chunk >> 2,      q0 = c0chunk & 3;
  int row1 = (c0chunk + 64) >> 2, q1 = (c0chunk + 64) & 3;
  const u16* Arow0 = A  + (long)(mt * 128 + row0) * K + q0 * 8;
  const u16* Arow1 = A  + (long)(mt * 128 + row1) * K + q1 * 8;
  const u16* Brow0 = Bt + (long)(nt * 128 + row0) * K + q0 * 8;
  const u16* Brow1 = Bt + (long)(nt * 128 + row1) * K + q1 * 8;
  u16* ldsA0 = As + (wid * 128) * 8;       // wave-uniform LDS base (lane*16B implicit)
  u16* ldsA1 = As + (wid * 128 + 64) * 8;
  u16* ldsB0 = Bs + (wid * 128) * 8;
  u16* ldsB1 = Bs + (wid * 128 + 64) * 8;
  f32x4 acc[4][4] = {};
  for (int k0 = 0; k0 < K; k0 += 32) {
    __syncthreads();   // prior iter's LDS reads done
    gload16(Arow0 + k0, ldsA0);
    gload16(Arow1 + k0, ldsA1);
    gload16(Brow0 + k0, ldsB0);
    gload16(Brow1 + k0, ldsB1);
    __syncthreads();   // staging complete (compiler emits vmcnt(0) before barrier)
    short8 af[4], bf[4];
    #pragma unroll
    for (int i = 0; i < 4; i++)
      af[i] = *(const short8*)(As + (mw + i * 16 + lr) * 32 + lg * 8);
    #pragma unroll
    for (int i = 0; i < 4; i++)
      bf[i] = *(const short8*)(Bs + (nw + i * 16 + lr) * 32 + lg * 8);
    #pragma unroll
    for (int i = 0; i < 4; i++)
      #pragma unroll
      for (int j = 0; j < 4; j++)
        acc[i][j] = __builtin_amdgcn_mfma_f32_16x16x32_bf16(af[i], bf[j], acc[i][j], 0, 0, 0);
  }
  #pragma unroll
  for (int i = 0; i < 4; i++) {
    #pragma unroll
    for (int j = 0; j < 4; j++) {
      int mbase = mt * 128 + mw + i * 16 + lg * 4;      // C/D: row=(lane>>4)*4+r
      int n     = nt * 128 + nw + j * 16 + lr;          //      col=lane&15
      #pragma unroll
      for (int r = 0; r < 4; r++) {
        float val = acc[i][j][r];
        int m = mbase + r;
        if (MODE == 0) {
          int b = m >> 11, t = m & (T_ - 1);
          int h = n / 192, f = n % 192;
          long o = (((long)(b * H_ + h)) * T_ + t) * HS_;
          if (f < 64)       Oq[o + f]       = f2bf(val * (0.03125f * LOG2E_));  // fold C^-0.5 * log2e
          else if (f < 128) Ok[o + f - 64]  = f2bf(val);
          else              Ov[o + f - 128] = f2bf(val);
        } else {
          Of[(long)m * D_ + n] = val;
        }
      }
    }
  }
}

// -------- transpose V [bh][T][64] -> Vt [bh][64][T]  +  per-tile column sums --------
__global__ void k_transpose_v(const u16* __restrict__ V, u16* __restrict__ Vt,
                              float* __restrict__ Partial) {
  __shared__ u16 tile[64][65];
  __shared__ float psum[4][64];
  int bh = blockIdx.z;
  int jt = blockIdx.x;          // tile index
  int t0 = jt * 64;
  int tx = threadIdx.x & 63, ty = threadIdx.x >> 6;
  const u16* src = V + (long)bh * T_ * HS_;
  u16* dst = Vt + (long)bh * T_ * HS_;
  #pragma unroll
  for (int i = 0; i < 64; i += 4)
    tile[ty + i][tx] = src[(long)(t0 + ty + i) * HS_ + tx];
  __syncthreads();
  #pragma unroll
  for (int i = 0; i < 64; i += 4)
    dst[(long)(ty + i) * T_ + t0 + tx] = tile[tx][ty + i];
  // per-tile column sums: thread (ty,tx) sums 16 rows of dim tx
  float s = 0.f;
  #pragma unroll
  for (int i = 0; i < 16; i++)
    s += bf2f(tile[ty * 16 + i][tx]);
  psum[ty][tx] = s;
  __syncthreads();
  if (threadIdx.x < 64)
    Partial[((long)bh * NTILE_ + jt) * HS_ + threadIdx.x] =
        psum[0][threadIdx.x] + psum[1][threadIdx.x] + psum[2][threadIdx.x] + psum[3][threadIdx.x];
}

// -------- suffix scan over tile sums: Suf[bh][j][d] = sum_{jt >= j} Partial[bh][jt][d] --------
__global__ void k_vscan(const float* __restrict__ Partial, float* __restrict__ Suf) {
  int bh = blockIdx.x;
  int d = threadIdx.x;
  const float* Pb = Partial + (long)bh * NTILE_ * HS_;
  float* Sb = Suf + (long)bh * (NTILE_ + 1) * HS_;
  float acc = 0.f;
  Sb[NTILE_ * HS_ + d] = 0.f;
  for (int j = NTILE_ - 1; j >= 0; j--) {
    acc += Pb[j * HS_ + d];
    Sb[j * HS_ + d] = acc;
  }
}

// ---------------- fused attention: swapped QK^T (S^T = K·Q^T) => P is lane-local in k ----------------
// No-max softmax (scale*log2e folded into Q); P = exp2; masked entries = 1.0 exactly.
// PV uses slot-matched operands: A = natural per-lane P packing (cvt_pk), B = V read at the
// same k-slot order (ds_read_b64 at cols 4*lg / 16+4*lg). No P LDS bounce, no cross-lane.
// Work-balanced: block x handles qt = x AND qt = NTILE-1-x  => exactly NTILE+1 tile-iters per block.
__global__ __launch_bounds__(256) void k_attn(
    const u16* __restrict__ Q, const u16* __restrict__ Kc,
    const u16* __restrict__ Vt, const float* __restrict__ Suf,
    u16* __restrict__ Mha) {
  __shared__ __align__(16) u16 Ks[64 * 72];
  __shared__ __align__(16) u16 Vs[64 * 72];
  int bh = blockIdx.y;
  int b = bh >> 4, h = bh & 15;
  int tid = threadIdx.x, wid = tid >> 6, lane = tid & 63;
  int lr = lane & 15, lg = lane >> 4;
  const u16* Qb = Q  + (long)bh * T_ * HS_;
  const u16* Kb = Kc + (long)bh * T_ * HS_;
  const u16* Vb = Vt + (long)bh * T_ * HS_;   // [64][T]
  int srow = tid >> 2, scol = (tid & 3) * 16;
  union U8 { unsigned u[4]; short8 s; };

  #pragma unroll 1
  for (int half = 0; half < 2; half++) {
    int qt = half ? (NTILE_ - 1 - (int)blockIdx.x) : (int)blockIdx.x;
    int qrow = qt * 64 + wid * 16 + lr;         // this lane's q row (B-operand col = lane&15)
    short8 qf0 = *(const short8*)(Qb + (long)qrow * HS_ + lg * 8);
    short8 qf1 = *(const short8*)(Qb + (long)qrow * HS_ + 32 + lg * 8);
    f32x4 accO[4] = {};                         // O[q=lg*4+r][d=fd*16+lr]
    float lpart = 0.f;                          // partial denom for q = lr
    const int jend = qt * 64;
    for (int j0 = 0; j0 <= jend; j0 += 64) {
      const bool diag = (j0 == jend);
      __syncthreads();
      *(short8*)(Ks + srow * 72 + scol)     = *(const short8*)(Kb + (long)(j0 + srow) * HS_ + scol);
      *(short8*)(Ks + srow * 72 + scol + 8) = *(const short8*)(Kb + (long)(j0 + srow) * HS_ + scol + 8);
      *(short8*)(Vs + srow * 72 + scol)     = *(const short8*)(Vb + (long)srow * T_ + j0 + scol);
      *(short8*)(Vs + srow * 72 + scol + 8) = *(const short8*)(Vb + (long)srow * T_ + j0 + scol + 8);
      __syncthreads();
      // S^T = K Q^T : lane holds S[q=lr][s = j0 + fn*16 + lg*4 + r]
      f32x4 s4[4];
      #pragma unroll
      for (int fn = 0; fn < 4; fn++) {
        short8 kb0 = *(const short8*)(Ks + (fn * 16 + lr) * 72 + lg * 8);
        short8 kb1 = *(const short8*)(Ks + (fn * 16 + lr) * 72 + 32 + lg * 8);
        f32x4 z = {};
        z = __builtin_amdgcn_mfma_f32_16x16x32_bf16(kb0, qf0, z, 0, 0, 0);
        z = __builtin_amdgcn_mfma_f32_16x16x32_bf16(kb1, qf1, z, 0, 0, 0);
        s4[fn] = z;
      }
      // no-max softmax: P = exp2(s2); masked -> exp2(0) = 1.0 (== exp(1e-9) in fp32)
      float p[4][4];
      float lp = 0.f;
      #pragma unroll
      for (int fn = 0; fn < 4; fn++) {
        #pragma unroll
        for (int r = 0; r < 4; r++) {
          float v = s4[fn][r];
          if (diag) {
            int s = j0 + fn * 16 + lg * 4 + r;
            v = (s <= qrow) ? v : 0.0f;        // faithful masked_fill(1e-9)
          }
          float pe = exp2f(v);
          p[fn][r] = pe;
          lp += pe;
        }
      }
      lpart += lp;
      // pack P into A-frags in natural slot order (k-slot kappa = 16*(w>>1) + 4*lg + 2*(w&1) + e)
      U8 pa0, pa1;
      pa0.u[0] = pkbf(p[0][0], p[0][1]); pa0.u[1] = pkbf(p[0][2], p[0][3]);
      pa0.u[2] = pkbf(p[1][0], p[1][1]); pa0.u[3] = pkbf(p[1][2], p[1][3]);
      pa1.u[0] = pkbf(p[2][0], p[2][1]); pa1.u[1] = pkbf(p[2][2], p[2][3]);
      pa1.u[2] = pkbf(p[3][0], p[3][1]); pa1.u[3] = pkbf(p[3][2], p[3][3]);
      // PV: B-frag reads V at the same slot order; accO[fd] += P·V
      #pragma unroll
      for (int fd = 0; fd < 4; fd++) {
        const u16* vrow = Vs + (fd * 16 + lr) * 72;
        U8 vb0, vb1;
        *(uint2*)&vb0.u[0] = *(const uint2*)(vrow + 4 * lg);
        *(uint2*)&vb0.u[2] = *(const uint2*)(vrow + 16 + 4 * lg);
        *(uint2*)&vb1.u[0] = *(const uint2*)(vrow + 32 + 4 * lg);
        *(uint2*)&vb1.u[2] = *(const uint2*)(vrow + 48 + 4 * lg);
        accO[fd] = __builtin_amdgcn_mfma_f32_16x16x32_bf16(pa0.s, vb0.s, accO[fd], 0, 0, 0);
        accO[fd] = __builtin_amdgcn_mfma_f32_16x16x32_bf16(pa1.s, vb1.s, accO[fd], 0, 0, 0);
      }
    }
    // denom: reduce lpart over the 4 lg-copies of each q, then redistribute to q = lg*4+r
    float ls = lpart;
    ls += __shfl_xor(ls, 16, 64);
    ls += __shfl_xor(ls, 32, 64);
    float lrun[4];
    #pragma unroll
    for (int r = 0; r < 4; r++)
      lrun[r] = __shfl(ls, lg * 4 + r, 64);    // holder lane of q=lg*4+r (lanes 0..15)
    // closed-form masked-suffix correction (pm = exp(1e-9) = 1.0)
    {
      int nmask = T_ - (qt + 1) * 64;
      const float* sufp = Suf + ((long)bh * (NTILE_ + 1) + (qt + 1)) * HS_;
      float sufv[4];
      #pragma unroll
      for (int fd = 0; fd < 4; fd++) sufv[fd] = sufp[fd * 16 + lr];
      #pragma unroll
      for (int r = 0; r < 4; r++) {
        lrun[r] += (float)nmask;
        #pragma unroll
        for (int fd = 0; fd < 4; fd++)
          accO[fd][r] += sufv[fd];
      }
    }
    #pragma unroll
    for (int fd = 0; fd < 4; fd++) {
      #pragma unroll
      for (int r = 0; r < 4; r++) {
        int trow = qt * 64 + wid * 16 + lg * 4 + r;
        int dcol = fd * 16 + lr;
        float o = accO[fd][r] / lrun[r];
        Mha[((long)(b * T_ + trow)) * D_ + h * HS_ + dcol] = f2bf(o);
      }
    }
    __syncthreads();
  }
}

extern "C" void kernel_launch(void* const* d_in, const int* in_sizes, int n_in,
                              void* d_out, int out_size, void* d_ws, size_t ws_size,
                              hipStream_t stream) {
  const float* x    = (const float*)d_in[0];
  const float* wqkv = (const float*)d_in[1];   // [16][1024][192]
  const float* wout = (const float*)d_in[2];   // [1024][1024]
  float* out = (float*)d_out;

  char* p = (char*)d_ws;
  u16* Xb    = (u16*)p; p += (size_t)M_ * D_ * 2;        // x as bf16 [8192][1024]
  u16* WqkvT = (u16*)p; p += (size_t)NQKV_ * D_ * 2;     // [3072][1024]  (n-major, k-contig)
  u16* WoutT = (u16*)p; p += (size_t)D_ * D_ * 2;        // [1024][1024]  W_out^T
  u16* Qw  = (u16*)p; p += (size_t)B_ * H_ * T_ * HS_ * 2;  // [B,H,T,64], pre-scaled by C^-0.5*log2e
  u16* Kw  = (u16*)p; p += (size_t)B_ * H_ * T_ * HS_ * 2;
  u16* Vw  = (u16*)p; p += (size_t)B_ * H_ * T_ * HS_ * 2;
  u16* Vtw = (u16*)p; p += (size_t)B_ * H_ * T_ * HS_ * 2;  // [B,H,64,T]
  u16* Mha = (u16*)p; p += (size_t)M_ * D_ * 2;             // [8192][1024]
  float* Suf = (float*)p; p += (size_t)B_ * H_ * (NTILE_ + 1) * HS_ * 4;  // [bh][33][64] fp32
  float* Part = (float*)p; p += (size_t)B_ * H_ * NTILE_ * HS_ * 4;       // [bh][32][64] fp32

  k_cvt_x<<<dim3(M_ * D_ / 4 / 256), dim3(256), 0, stream>>>(x, Xb, M_ * D_ / 4);
  k_transpose_cvt<<<dim3(192 / 32, D_ / 32, H_), dim3(32, 8), 0, stream>>>(
      wqkv, WqkvT, D_, 192, (long)D_ * 192, (long)192 * D_);
  k_transpose_cvt<<<dim3(D_ / 32, D_ / 32, 1), dim3(32, 8), 0, stream>>>(
      wout, WoutT, D_, D_, 0, 0);
  k_gemm<0><<<dim3(M_ / 128, NQKV_ / 128), dim3(256), 0, stream>>>(
      Xb, WqkvT, Qw, Kw, Vw, nullptr, D_);
  k_transpose_v<<<dim3(T_ / 64, 1, B_ * H_), dim3(256), 0, stream>>>(Vw, Vtw, Part);
  k_vscan<<<dim3(B_ * H_), dim3(64), 0, stream>>>(Part, Suf);
  k_attn<<<dim3(NTILE_ / 2, B_ * H_), dim3(256), 0, stream>>>(Qw, Kw, Vtw, Suf, Mha);
  k_gemm<1><<<dim3(M_ / 128, D_ / 128), dim3(256), 0, stream>>>(
      Mha, WoutT, nullptr, nullptr, nullptr, out, D_);
}